// Round 10
// baseline (3321.539 us; speedup 1.0000x reference)
//
#include <hip/hip_runtime.h>
#include <math.h>

#define TSTEPS 512
#define BN 4096
#define NBLK 256      // 1 block per CU; replica r = blocks with blockIdx%8==r
#define NTHR 576      // 9 waves: wave 0 updater, waves 1..8 gather
#define NPB 128       // neurons per block (BN / 32 blocks-per-replica)
#define NREP 8
#define BPR 32        // blocks per replica
#define NWREP 128     // 32-bit mask words per replica mailbox (4096/32)
#define NGW 8
#define WPW 16        // mailbox words owned per gather wave

typedef unsigned long long u64;

// sc0 load: bypass L1, read the XCD's shared L2 (where same-XCD producers'
// plain stores land). This is the fast intra-XCD spike path.
__device__ __forceinline__ u64 ld_l2(const u64* p) {
    u64 v;
    asm volatile("global_load_dwordx2 %0, %1, off sc0\n\ts_waitcnt vmcnt(0)"
                 : "=v"(v) : "v"(p) : "memory");
    return v;
}
// plain store: write-through L1 into this XCD's L2 (visible to sc0 loads).
__device__ __forceinline__ void st_l2(u64* p, u64 v) {
    asm volatile("global_store_dwordx2 %0, %1, off" :: "v"(p), "v"(v) : "memory");
}
__device__ __forceinline__ u64 ld_agent(const u64* p) {
    return __hip_atomic_load(p, __ATOMIC_RELAXED, __HIP_MEMORY_SCOPE_AGENT);
}
__device__ __forceinline__ void st_agent(u64* p, u64 v) {
    __hip_atomic_store(p, v, __ATOMIC_RELAXED, __HIP_MEMORY_SCOPE_AGENT);
}
__device__ __forceinline__ void st_flag(unsigned* p, unsigned v) {
    __hip_atomic_store(p, v, __ATOMIC_RELEASE, __HIP_MEMORY_SCOPE_WORKGROUP);
}
__device__ __forceinline__ unsigned ld_flag(const unsigned* p) {
    return __hip_atomic_load(p, __ATOMIC_ACQUIRE, __HIP_MEMORY_SCOPE_WORKGROUP);
}

// 8 independent replicas (one per XCD if blockIdx%8 round-robin holds), each
// computing the FULL network redundantly with intra-replica (L2-local) spike
// exchange. Producers ALWAYS dual-publish: plain store to the replica's fast
// mailbox (L2) + agent store to a fallback mailbox (fabric). Pollers use sc0
// fast polls and consult the fallback every 8th retry -> correctness never
// depends on the XCD mapping. Replicas are bit-identical (fixed word/bit/tree
// order); only replica 0 writes outputs.
template<bool TR>
__global__ __launch_bounds__(NTHR, 1)
void glif_kernel(const float* __restrict__ x_seq, const float* __restrict__ w,
                 const float* __restrict__ b_in, const float* __restrict__ v0,
                 const float* __restrict__ Ia0, const float* __restrict__ vth_in,
                 const float* __restrict__ vrst_in, const float* __restrict__ vrest_in,
                 const float* __restrict__ cm_in, const float* __restrict__ tau_in,
                 const float* __restrict__ k_in, const float* __restrict__ asc_in,
                 const float* __restrict__ mask_in,
                 float* __restrict__ out_s, float* __restrict__ out_v,
                 float* __restrict__ out_vf, float* __restrict__ out_if,
                 u64* __restrict__ fastmb, u64* __restrict__ fbmb,
                 unsigned* __restrict__ bar, float* __restrict__ wT)
{
    __shared__ float    tile[64][65];          // transpose staging (phase 0)
    __shared__ int      wlist[NGW][512];       // per-gather-wave column lists
    __shared__ float4   part4[4][NGW][32];     // 4-deep ring: float[4][8][128]
    __shared__ unsigned flags[NGW];

    const int blk = blockIdx.x;
    const int tid = threadIdx.x;
    const int wv = tid >> 6;                   // wave 0..8
    const int ln = tid & 63;
    const int rep = blk & 7;                   // replica (heuristically = XCD)
    const int rank = blk >> 3;                 // 0..31 within replica
    const int n0 = rank * NPB;

    // ---- Phase 0: transpose w -> wT, folding mask into columns (shared, once)
    if (TR) {
        for (int tt = 0; tt < 16; ++tt) {
            int tile_id = blk + tt * NBLK;     // 4096 tiles of 64x64
            int ti = tile_id >> 6, tj = tile_id & 63;
            if (tid < 512) {
                int c = tid & 63, r0 = tid >> 6;
#pragma unroll
                for (int rr = 0; rr < 8; ++rr) {
                    int r = r0 + rr * 8;
                    tile[r][c] = w[(size_t)(ti * 64 + r) * BN + tj * 64 + c];
                }
            }
            __syncthreads();
            if (tid < 512) {
                int rw = tid & 63, c0 = tid >> 6;
#pragma unroll
                for (int cc = 0; cc < 8; ++cc) {
                    int cw = c0 + cc * 8;
                    float mcol = mask_in[tj * 64 + cw];
                    wT[(size_t)(tj * 64 + cw) * BN + ti * 64 + rw] = tile[rw][cw] * mcol;
                }
            }
            __syncthreads();
        }
    }

    if (tid < NGW) flags[tid] = 0;

    // ---- single grid barrier: wT complete before step loop
    __syncthreads();
    if (tid == 0) {
        __threadfence();
        __hip_atomic_fetch_add(bar, 1u, __ATOMIC_ACQ_REL, __HIP_MEMORY_SCOPE_AGENT);
        while (__hip_atomic_load(bar, __ATOMIC_RELAXED, __HIP_MEMORY_SCOPE_AGENT) < NBLK) {
            __builtin_amdgcn_s_sleep(8);
        }
        __threadfence();
    }
    __syncthreads();

    u64* fastP = fastmb + (size_t)rep * 2 * NWREP;
    u64* fbP   = fbmb   + (size_t)rep * 2 * NWREP;

    if (wv == 0) {
        // ================= WAVE 0: updater (2 neurons / lane) =================
        const int nlo = n0 + ln, nhi = n0 + 64 + ln;
        float vA = v0[nlo], vB = v0[nhi];
        float I0A = Ia0[2 * nlo], I1A = Ia0[2 * nlo + 1];
        float I0B = Ia0[2 * nhi], I1B = Ia0[2 * nhi + 1];
        float bbA = b_in[nlo], bbB = b_in[nhi];
        float vthA = vth_in[nlo], vthB = vth_in[nhi];
        float vrA = vrst_in[nlo], vrB = vrst_in[nhi];
        float veA = vrest_in[nlo], veB = vrest_in[nhi];
        float cmA = cm_in[nlo], cmB = cm_in[nhi];
        float tauA = tau_in[nlo], tauB = tau_in[nhi];
        float mkA = mask_in[nlo], mkB = mask_in[nhi];
        float aaA = (float)exp((double)(-1.0f / tauA));
        float aaB = (float)exp((double)(-1.0f / tauB));
        float b0A = (float)exp((double)(-k_in[2 * nlo]));
        float b1A = (float)exp((double)(-k_in[2 * nlo + 1]));
        float b0B = (float)exp((double)(-k_in[2 * nhi]));
        float b1B = (float)exp((double)(-k_in[2 * nhi + 1]));
        float s0A = asc_in[2 * nlo], s1A = asc_in[2 * nlo + 1];
        float s0B = asc_in[2 * nhi], s1B = asc_in[2 * nhi + 1];

        for (int t = 0; t < TSTEPS; ++t) {
            float xlo = x_seq[(size_t)t * BN + nlo];    // overlap flag wait
            float xhi = x_seq[(size_t)t * BN + nhi];

            {   // spin on local LDS flags (fast intra-block detect)
                const unsigned want = (unsigned)(t + 1);
                const unsigned* fp = &flags[ln & 7];
                while (ld_flag(fp) < want) {}
            }
            const float* pf = reinterpret_cast<const float*>(&part4[t & 3][0][0]);
            float lA, lB;
            {
                float p0 = pf[ln],       p1 = pf[128 + ln], p2 = pf[256 + ln], p3 = pf[384 + ln];
                float p4 = pf[512 + ln], p5 = pf[640 + ln], p6 = pf[768 + ln], p7 = pf[896 + ln];
                lA = ((p0 + p1) + (p2 + p3)) + ((p4 + p5) + (p6 + p7));
            }
            {
                int h = 64 + ln;
                float p0 = pf[h],       p1 = pf[128 + h], p2 = pf[256 + h], p3 = pf[384 + h];
                float p4 = pf[512 + h], p5 = pf[640 + h], p6 = pf[768 + h], p7 = pf[896 + h];
                lB = ((p0 + p1) + (p2 + p3)) + ((p4 + p5) + (p6 + p7));
            }
            // reference op order
            float xxA = (xlo + bbA) + lA;
            float xxB = (xhi + bbB) + lB;
            float vpA = (veA + (tauA * (xxA + (I0A + I1A))) / cmA);
            vpA = vpA + (vA - vpA) * aaA;
            float vpB = (veB + (tauB * (xxB + (I0B + I1B))) / cmB);
            vpB = vpB + (vB - vpB) * aaB;
            float sA = (((vpA - vthA) / (vthA - vrA)) > 0.0f) ? mkA : 0.0f;
            float sB = (((vpB - vthB) / (vthB - vrB)) > 0.0f) ? mkB : 0.0f;
            u64 bal_lo = __ballot(sA != 0.0f);          // neurons n0..n0+63
            u64 bal_hi = __ballot(sB != 0.0f);          // neurons n0+64..n0+127
            if (ln < 4) {                               // publish 4 tagged words
                u64 bsel = (ln & 2) ? bal_hi : bal_lo;
                unsigned pay = (ln & 1) ? (unsigned)(bsel >> 32) : (unsigned)bsel;
                u64 ent = (((u64)(t + 1)) << 32) | (u64)pay;
                size_t off = (size_t)((t + 1) & 1) * NWREP + rank * 4 + ln;
                st_l2(fastP + off, ent);                // L2-local fast path
                st_agent(fbP + off, ent);               // fabric fallback (always)
            }
            float voA = vpA - (vpA - vrA) * sA;         // HARD_RESET
            float voB = vpB - (vpB - vrB) * sB;
            I0A = I0A * b0A + s0A * sA; I1A = I1A * b1A + s1A * sA;
            I0B = I0B * b0B + s0B * sB; I1B = I1B * b1B + s1B * sB;
            vA = voA; vB = voB;
            if (rep == 0) {
                out_s[(size_t)t * BN + nlo] = sA;
                out_s[(size_t)t * BN + nhi] = sB;
                out_v[(size_t)t * BN + nlo] = voA;
                out_v[(size_t)t * BN + nhi] = voB;
            }
        }
        if (rep == 0) {
            out_vf[nlo] = vA; out_vf[nhi] = vB;
            out_if[2 * nlo] = I0A; out_if[2 * nlo + 1] = I1A;
            out_if[2 * nhi] = I0B; out_if[2 * nhi + 1] = I1B;
        }
    } else {
        // ============ WAVES 1..8: gather over 16 mailbox words each ============
        const int gw = wv - 1;
        const int widx = gw * WPW + (ln >> 2);  // word 0..127 of replica mailbox
        const int sub = ln & 3;                 // byte of the 32-bit payload
        const int cbase = widx * 32 + sub * 8;
        const int cslot = ln >> 5;              // 2 columns per round
        const int r32 = ln & 31;                // 32 lanes x float4 = 128 rows
        const float* wb4 = wT + n0 + r32 * 4;

        for (int t = 0; t < TSTEPS; ++t) {
            const u64* pF = fastP + (size_t)(t & 1) * NWREP + widx;
            const u64* pB = fbP   + (size_t)(t & 1) * NWREP + widx;
            const unsigned want = (unsigned)t;
            u64 ev; int it = 0;
            for (;;) {
                u64 A = ld_l2(pF);
                if ((unsigned)(A >> 32) == want) { ev = A; break; }
                if (((++it) & 7) == 0) {        // fallback: mapping-independent
                    u64 B = ld_agent(pB);
                    if ((unsigned)(B >> 32) == want) { ev = B; break; }
                }
            }
            unsigned byte = ((unsigned)ev >> (8 * sub)) & 0xFFu;

            // ---- in-wave compaction (fixed ascending order => deterministic)
            int c = __popc(byte);
            int x = c;
#pragma unroll
            for (int d = 1; d < 64; d <<= 1) {
                int y = __shfl_up(x, d);
                if (ln >= d) x += y;
            }
            const int kw = __shfl(x, 63);
            int base = x - c;
            while (byte) { int bp = __ffs(byte) - 1; byte &= byte - 1; wlist[gw][base++] = cbase + bp; }

            // ---- pipelined gather: 2 columns/round x 32 lanes x float4
            if (TR) {
                float4 acc = make_float4(0.f, 0.f, 0.f, 0.f);
                const int R = (kw + 1) >> 1;
                for (int r = 0; r < R; r += 8) {
#pragma unroll
                    for (int u = 0; u < 8; ++u) {
                        int idx = (r + u) * 2 + cslot;
                        bool pg = idx < kw;
                        int j = wlist[gw][pg ? idx : 0];
                        float m = pg ? 1.0f : 0.0f;
                        const float4 wv4 = *reinterpret_cast<const float4*>(wb4 + (size_t)j * BN);
                        acc.x = fmaf(wv4.x, m, acc.x);
                        acc.y = fmaf(wv4.y, m, acc.y);
                        acc.z = fmaf(wv4.z, m, acc.z);
                        acc.w = fmaf(wv4.w, m, acc.w);
                    }
                }
                acc.x += __shfl_xor(acc.x, 32);
                acc.y += __shfl_xor(acc.y, 32);
                acc.z += __shfl_xor(acc.z, 32);
                acc.w += __shfl_xor(acc.w, 32);
                if (ln < 32) part4[t & 3][gw][r32] = acc;
            } else {
                float a0 = 0.f, a1 = 0.f;
                const float* wr0 = w + (size_t)(n0 + ln) * BN;
                const float* wr1 = w + (size_t)(n0 + 64 + ln) * BN;
                for (int i = 0; i < kw; ++i) {
                    int j = wlist[gw][i];
                    a0 = fmaf(wr0[j], mask_in[j], a0);
                    a1 = fmaf(wr1[j], mask_in[j], a1);
                }
                float* pp = reinterpret_cast<float*>(&part4[t & 3][gw][0]);
                pp[ln] = a0; pp[64 + ln] = a1;
            }
            if (ln == 0) st_flag(&flags[gw], (unsigned)(t + 1));  // release
        }
    }
}

extern "C" void kernel_launch(void* const* d_in, const int* in_sizes, int n_in,
                              void* d_out, int out_size, void* d_ws, size_t ws_size,
                              hipStream_t stream)
{
    const float* x_seq = (const float*)d_in[0];
    const float* w     = (const float*)d_in[1];
    const float* b     = (const float*)d_in[2];
    const float* v0    = (const float*)d_in[3];
    const float* Ia0   = (const float*)d_in[4];
    const float* vth   = (const float*)d_in[5];
    const float* vrst  = (const float*)d_in[6];
    const float* vrest = (const float*)d_in[7];
    const float* cm    = (const float*)d_in[8];
    const float* tau   = (const float*)d_in[9];
    const float* k     = (const float*)d_in[10];
    const float* asc   = (const float*)d_in[11];
    const float* mask  = (const float*)d_in[12];

    float* out_s  = (float*)d_out;
    float* out_v  = out_s + (size_t)TSTEPS * BN;
    float* out_vf = out_v + (size_t)TSTEPS * BN;
    float* out_if = out_vf + BN;

    // ws layout: fast mailboxes (8 rep x 2 par x 128 w x 8B = 16KB),
    // fallback mailboxes (16KB), barrier, then wT (64MB)
    u64* fastmb   = (u64*)d_ws;
    u64* fbmb     = (u64*)((char*)d_ws + 16384);
    unsigned* bar = (unsigned*)((char*)d_ws + 32768);
    float* wT     = (float*)((char*)d_ws + 33024);

    const size_t need = 33024 + (size_t)BN * BN * sizeof(float);
    const bool tr = (ws_size >= need);

    // zero mailboxes + barrier (inside graph -> resets every replay)
    hipMemsetAsync(d_ws, 0, 33024, stream);

    if (tr) {
        glif_kernel<true><<<NBLK, NTHR, 0, stream>>>(
            x_seq, w, b, v0, Ia0, vth, vrst, vrest, cm, tau, k, asc, mask,
            out_s, out_v, out_vf, out_if, fastmb, fbmb, bar, wT);
    } else {
        glif_kernel<false><<<NBLK, NTHR, 0, stream>>>(
            x_seq, w, b, v0, Ia0, vth, vrst, vrest, cm, tau, k, asc, mask,
            out_s, out_v, out_vf, out_if, fastmb, fbmb, bar, (float*)w);
    }
}

// Round 12
// 1891.716 us; speedup vs baseline: 1.7558x; 1.7558x over previous
//
#include <hip/hip_runtime.h>
#include <math.h>

#define TSTEPS 512
#define BN 4096
#define NBLK 64
#define NTHR 576      // 9 waves: wave 0 = updater, waves 1..8 = gather waves
#define NPB 64        // neurons per block
#define NGW 8         // gather waves
#define ESTRIDE 16    // u64s per mailbox entry: one 128-B line per block

typedef unsigned long long u64;

__device__ __forceinline__ void st_agent(u64* p, u64 v) {
    __hip_atomic_store(p, v, __ATOMIC_RELAXED, __HIP_MEMORY_SCOPE_AGENT);
}
__device__ __forceinline__ void st_flag(unsigned* p, unsigned v) {
    __hip_atomic_store(p, v, __ATOMIC_RELEASE, __HIP_MEMORY_SCOPE_WORKGROUP);
}
__device__ __forceinline__ unsigned ld_flag(const unsigned* p) {
    return __hip_atomic_load(p, __ATOMIC_ACQUIRE, __HIP_MEMORY_SCOPE_WORKGROUP);
}

// Rolling-window poll, SELF-CONTAINED asm block (fixes R11's register-reuse
// corruption: all 4 slot registers are owned by the block, and the vmcnt(0)
// drain happens inside it, so no in-flight load can land on a reused VGPR).
// 4 outstanding tag-loads to the same address, oldest checked with counted
// s_waitcnt vmcnt(3) -> the line is sampled ~4x per fabric RTT. Exit is
// wave-uniform (s_cbranch_vccz on v_cmp_lt_u64): loop until NO lane's oldest
// slot is below thresh -- the wave needs all its 8 entries anyway.
// Tag algebra: this parity slot can only hold tag t-2 or t when we want t
// (t+2 provably unpublishable until every consumer read t), so any slot
// >= thresh IS the unique tag-t entry; max(s0..s3) selects one branch-free.
// 8B dwordx2 loads are single-copy atomic -> tag+payload arrive together.
__device__ __forceinline__ u64 poll_roll(const u64* p, u64 thresh) {
    u64 s0, s1, s2, s3;
    asm volatile(
        "global_load_dwordx2 %0, %4, off sc1\n\t"
        "global_load_dwordx2 %1, %4, off sc1\n\t"
        "global_load_dwordx2 %2, %4, off sc1\n\t"
        "global_load_dwordx2 %3, %4, off sc1\n\t"
        "GLIF_poll_%=:\n\t"
        "s_waitcnt vmcnt(3)\n\t"
        "v_cmp_lt_u64 vcc, %0, %5\n\t"
        "s_cbranch_vccz GLIF_done_%=\n\t"
        "global_load_dwordx2 %0, %4, off sc1\n\t"
        "s_waitcnt vmcnt(3)\n\t"
        "v_cmp_lt_u64 vcc, %1, %5\n\t"
        "s_cbranch_vccz GLIF_done_%=\n\t"
        "global_load_dwordx2 %1, %4, off sc1\n\t"
        "s_waitcnt vmcnt(3)\n\t"
        "v_cmp_lt_u64 vcc, %2, %5\n\t"
        "s_cbranch_vccz GLIF_done_%=\n\t"
        "global_load_dwordx2 %2, %4, off sc1\n\t"
        "s_waitcnt vmcnt(3)\n\t"
        "v_cmp_lt_u64 vcc, %3, %5\n\t"
        "s_cbranch_vccz GLIF_done_%=\n\t"
        "global_load_dwordx2 %3, %4, off sc1\n\t"
        "s_branch GLIF_poll_%=\n\t"
        "GLIF_done_%=:\n\t"
        "s_waitcnt vmcnt(0)"
        : "=&v"(s0), "=&v"(s1), "=&v"(s2), "=&v"(s3)
        : "v"(p), "v"(thresh)
        : "vcc", "memory");
    u64 m01 = (s0 > s1) ? s0 : s1;
    u64 m23 = (s2 > s3) ? s2 : s3;
    return (m01 > m23) ? m01 : m23;
}

// Persistent kernel, 64 blocks x 576 threads (9 waves). Structure = R6 (best):
//  wave 0   : pure updater. Spins on 8 LDS flags, combines partials (fixed
//             tree), updates 64 neurons, publishes 2 tagged mailbox words.
//  waves 1-8: free-running gather waves, no block barrier in the step loop.
//             Rolling-window poll of own mailbox entry word, 64-lane scan ->
//             compacted column list, pipelined float4 gather of mask-scaled
//             wT, shfl reduce, write partials into 4-deep LDS ring, release
//             monotonic LDS flag.
// Determinism: fixed word/bit/tree order everywhere.
template<bool TR>
__global__ __launch_bounds__(NTHR, 1)
void glif_kernel(const float* __restrict__ x_seq, const float* __restrict__ w,
                 const float* __restrict__ b_in, const float* __restrict__ v0,
                 const float* __restrict__ Ia0, const float* __restrict__ vth_in,
                 const float* __restrict__ vrst_in, const float* __restrict__ vrest_in,
                 const float* __restrict__ cm_in, const float* __restrict__ tau_in,
                 const float* __restrict__ k_in, const float* __restrict__ asc_in,
                 const float* __restrict__ mask_in,
                 float* __restrict__ out_s, float* __restrict__ out_v,
                 float* __restrict__ out_vf, float* __restrict__ out_if,
                 u64* __restrict__ sbuf, unsigned* __restrict__ bar,
                 float* __restrict__ wT)
{
    __shared__ float    tile[64][65];          // transpose staging (phase 0)
    __shared__ int      wlist[NGW][512];       // per-gather-wave column lists
    __shared__ float4   partials[4][NGW][16];  // 4-deep ring of GEMV partials
    __shared__ unsigned flags[NGW];            // monotonic step tags

    const int blk = blockIdx.x;
    const int tid = threadIdx.x;
    const int n0 = blk * NPB;
    const int wv = tid >> 6;                   // wave 0..8
    const int ln = tid & 63;

    // ---- Phase 0: transpose w -> wT, folding mask into columns
    if (TR) {
        for (int tt = 0; tt < 64; ++tt) {
            int tile_id = blk + tt * NBLK;     // 4096 tiles of 64x64
            int ti = tile_id >> 6, tj = tile_id & 63;
            if (tid < 512) {
                int c = tid & 63, r0 = tid >> 6;
#pragma unroll
                for (int rr = 0; rr < 8; ++rr) {
                    int r = r0 + rr * 8;
                    tile[r][c] = w[(size_t)(ti * 64 + r) * BN + tj * 64 + c];
                }
            }
            __syncthreads();
            if (tid < 512) {
                int rw = tid & 63, c0 = tid >> 6;
#pragma unroll
                for (int cc = 0; cc < 8; ++cc) {
                    int cw = c0 + cc * 8;
                    float mcol = mask_in[tj * 64 + cw];
                    wT[(size_t)(tj * 64 + cw) * BN + ti * 64 + rw] = tile[rw][cw] * mcol;
                }
            }
            __syncthreads();
        }
    }

    if (tid < NGW) flags[tid] = 0;

    // ---- single grid barrier: wT complete before step loop
    __syncthreads();
    if (tid == 0) {
        __threadfence();
        __hip_atomic_fetch_add(bar, 1u, __ATOMIC_ACQ_REL, __HIP_MEMORY_SCOPE_AGENT);
        while (__hip_atomic_load(bar, __ATOMIC_RELAXED, __HIP_MEMORY_SCOPE_AGENT) < NBLK) {
            __builtin_amdgcn_s_sleep(8);
        }
        __threadfence();
    }
    __syncthreads();

    if (wv == 0) {
        // ================= WAVE 0: pure updater =================
        const int n = n0 + ln;
        float v, I0, I1, bb, aa, bd0, bd1, as0, as1, vth, vrst, vrest, cm, tau, msk;
        v = v0[n]; I0 = Ia0[2 * n]; I1 = Ia0[2 * n + 1];
        bb = b_in[n]; vth = vth_in[n]; vrst = vrst_in[n]; vrest = vrest_in[n];
        cm = cm_in[n]; tau = tau_in[n]; msk = mask_in[n];
        aa  = (float)exp((double)(-1.0f / tau));
        bd0 = (float)exp((double)(-k_in[2 * n]));
        bd1 = (float)exp((double)(-k_in[2 * n + 1]));
        as0 = asc_in[2 * n]; as1 = asc_in[2 * n + 1];

        for (int t = 0; t < TSTEPS; ++t) {
            float xt = x_seq[(size_t)t * BN + n];       // overlaps flag wait

            {   // lanes spin on one flag each (8 flags, lanes mirror mod 8)
                const unsigned want = (unsigned)(t + 1);
                const unsigned* fp = &flags[ln & 7];
                while (ld_flag(fp) < want) {}
            }
            const float* pf = reinterpret_cast<const float*>(&partials[t & 3][0][0]);
            float l0 = pf[ln],        l1 = pf[64 + ln],  l2 = pf[128 + ln], l3 = pf[192 + ln];
            float l4 = pf[256 + ln],  l5 = pf[320 + ln], l6 = pf[384 + ln], l7 = pf[448 + ln];
            float lin = ((l0 + l1) + (l2 + l3)) + ((l4 + l5) + (l6 + l7));
            float xx = (xt + bb) + lin;
            float Isum = I0 + I1;
            float vinf = vrest + (tau * (xx + Isum)) / cm;
            float vp = vinf + (v - vinf) * aa;
            float uu = (vp - vth) / (vth - vrst);
            float s = (uu > 0.0f) ? msk : 0.0f;
            u64 bal = __ballot(s != 0.0f);              // bit l = neuron n0+l
            u64 tagw = ((u64)(t + 1)) << 32;
            u64* dst = sbuf + ((size_t)((t + 1) & 1) * NBLK + blk) * ESTRIDE;
            if (ln < 2) st_agent(dst + ln, tagw | (u64)(unsigned)(bal >> (32 * ln)));
            float vpost = vp - (vp - vrst) * s;         // HARD_RESET
            I0 = I0 * bd0 + as0 * s;
            I1 = I1 * bd1 + as1 * s;
            v = vpost;
            out_s[(size_t)t * BN + n] = s;
            out_v[(size_t)t * BN + n] = vpost;
        }
        out_vf[n] = v;
        out_if[2 * n] = I0;
        out_if[2 * n + 1] = I1;
    } else {
        // ================= WAVES 1..8: free-running gather =================
        const int gw = wv - 1;
        const int e = ln >> 3;                  // entry within this wave's 8
        const int sub = ln & 7;                 // byte 0..7 of the 64-bit mask
        const int wsel = sub >> 2;              // tagged word 0 or 1
        const int bshift = 8 * (sub & 3);
        const int entry = gw * 8 + e;
        const int cbase = (entry << 6) + (sub << 3);
        const int cslot = ln >> 4, l16 = ln & 15;  // 4 cols/round, 16 lanes/col
        const float* wb4 = wT + n0 + l16 * 4;

        for (int t = 0; t < TSTEPS; ++t) {
            // ---- rolling-window poll (tag-monotonic slot, >= check)
            const u64* p = sbuf + ((size_t)(t & 1) * NBLK + entry) * ESTRIDE + wsel;
            const u64 thresh = ((u64)t) << 32;
            u64 ev = poll_roll(p, thresh);
            unsigned byte = ((unsigned)ev >> bshift) & 0xFFu;

            // ---- in-wave compaction (fixed order => deterministic)
            int c = __popc(byte);
            int x = c;
#pragma unroll
            for (int d = 1; d < 64; d <<= 1) {
                int y = __shfl_up(x, d);
                if (ln >= d) x += y;
            }
            const int kw = __shfl(x, 63);
            int base = x - c;
            while (byte) { int bp = __ffs(byte) - 1; byte &= byte - 1; wlist[gw][base++] = cbase + bp; }

            // ---- pipelined gather-GEMV over this wave's columns
            if (TR) {
                float4 acc = make_float4(0.f, 0.f, 0.f, 0.f);
                const int R = (kw + 3) >> 2;     // rounds of 4 columns
                for (int r = 0; r < R; r += 8) {
#pragma unroll
                    for (int u = 0; u < 8; ++u) {
                        int idx = (r + u) * 4 + cslot;
                        bool pg = idx < kw;
                        int j = wlist[gw][pg ? idx : 0];
                        float m = pg ? 1.0f : 0.0f;
                        const float4 wvv = *reinterpret_cast<const float4*>(wb4 + ((size_t)j << 12));
                        acc.x = fmaf(wvv.x, m, acc.x);
                        acc.y = fmaf(wvv.y, m, acc.y);
                        acc.z = fmaf(wvv.z, m, acc.z);
                        acc.w = fmaf(wvv.w, m, acc.w);
                    }
                }
#pragma unroll
                for (int d = 16; d < 64; d <<= 1) {
                    acc.x += __shfl_xor(acc.x, d);
                    acc.y += __shfl_xor(acc.y, d);
                    acc.z += __shfl_xor(acc.z, d);
                    acc.w += __shfl_xor(acc.w, d);
                }
                if (ln < 16) partials[t & 3][gw][ln] = acc;
            } else {
                float accs = 0.f;
                const float* wrow = w + (size_t)(n0 + ln) * BN;
                for (int i = 0; i < kw; ++i) {
                    int j = wlist[gw][i];
                    accs = fmaf(wrow[j], mask_in[j], accs);
                }
                reinterpret_cast<float*>(&partials[t & 3][gw][0])[ln] = accs;
            }
            if (ln == 0) st_flag(&flags[gw], (unsigned)(t + 1));  // release
        }
    }
}

extern "C" void kernel_launch(void* const* d_in, const int* in_sizes, int n_in,
                              void* d_out, int out_size, void* d_ws, size_t ws_size,
                              hipStream_t stream)
{
    const float* x_seq = (const float*)d_in[0];
    const float* w     = (const float*)d_in[1];
    const float* b     = (const float*)d_in[2];
    const float* v0    = (const float*)d_in[3];
    const float* Ia0   = (const float*)d_in[4];
    const float* vth   = (const float*)d_in[5];
    const float* vrst  = (const float*)d_in[6];
    const float* vrest = (const float*)d_in[7];
    const float* cm    = (const float*)d_in[8];
    const float* tau   = (const float*)d_in[9];
    const float* k     = (const float*)d_in[10];
    const float* asc   = (const float*)d_in[11];
    const float* mask  = (const float*)d_in[12];

    float* out_s  = (float*)d_out;
    float* out_v  = out_s + (size_t)TSTEPS * BN;
    float* out_vf = out_v + (size_t)TSTEPS * BN;
    float* out_if = out_vf + BN;

    // mailbox: 2 parities x 64 blocks x 128-B line = 16 KiB
    const size_t mb_bytes = (size_t)2 * NBLK * ESTRIDE * sizeof(u64);
    u64* sbuf     = (u64*)d_ws;
    unsigned* bar = (unsigned*)((char*)d_ws + mb_bytes);
    float* wT     = (float*)((char*)d_ws + mb_bytes + 256);

    const size_t need = mb_bytes + 256 + (size_t)BN * BN * sizeof(float);
    const bool tr = (ws_size >= need);

    // zero mailbox tags + barrier counter (inside graph -> resets every replay)
    hipMemsetAsync(d_ws, 0, mb_bytes + 256, stream);

    if (tr) {
        glif_kernel<true><<<NBLK, NTHR, 0, stream>>>(
            x_seq, w, b, v0, Ia0, vth, vrst, vrest, cm, tau, k, asc, mask,
            out_s, out_v, out_vf, out_if, sbuf, bar, wT);
    } else {
        glif_kernel<false><<<NBLK, NTHR, 0, stream>>>(
            x_seq, w, b, v0, Ia0, vth, vrst, vrest, cm, tau, k, asc, mask,
            out_s, out_v, out_vf, out_if, sbuf, bar, (float*)w);
    }
}

// Round 14
// 1648.803 us; speedup vs baseline: 2.0145x; 1.1473x over previous
//
#include <hip/hip_runtime.h>
#include <math.h>

#define TSTEPS 512
#define BN 4096
#define NBLK 64
#define NTHR 576      // 9 waves: wave 0 = updater, waves 1..8 = gather waves
#define NPB 64        // neurons per block
#define NGW 8         // gather waves
#define ESTRIDE 16    // u64s per mailbox entry: one 128-B line per block

typedef unsigned long long u64;

__device__ __forceinline__ u64 ld_agent(const u64* p) {
    return __hip_atomic_load(p, __ATOMIC_RELAXED, __HIP_MEMORY_SCOPE_AGENT);
}
__device__ __forceinline__ void st_agent(u64* p, u64 v) {
    __hip_atomic_store(p, v, __ATOMIC_RELAXED, __HIP_MEMORY_SCOPE_AGENT);
}
__device__ __forceinline__ void st_flag(unsigned* p, unsigned v) {
    __hip_atomic_store(p, v, __ATOMIC_RELEASE, __HIP_MEMORY_SCOPE_WORKGROUP);
}
__device__ __forceinline__ unsigned ld_flag(const unsigned* p) {
    return __hip_atomic_load(p, __ATOMIC_ACQUIRE, __HIP_MEMORY_SCOPE_WORKGROUP);
}

// Persistent kernel, 64 blocks x 576 threads (9 waves). R6 structure — the
// measured optimum across 13 rounds of structural/mechanism experiments:
//  wave 0   : pure updater. Spins on 8 LDS flags, combines partials (fixed
//             tree), updates 64 neurons, publishes 2 tagged mailbox words.
//  waves 1-8: free-running gather waves, NO block barrier in the step loop.
//             Poll own mailbox entries (2 loads in flight), 64-lane scan ->
//             compacted column list, pipelined float4 gather of mask-scaled
//             wT, shfl reduce, write partials into 4-deep LDS ring, release
//             monotonic LDS flag.
// Race-freedom: publish(t+1) by any block requires all its gather waves to
// have flagged t, which requires their reads of mailbox step t done; global
// publish(t+2) therefore orders after every consumer read of t, so the
// 2-parity mailbox + 4-deep partials ring cannot be overwritten early.
// Determinism: fixed word/bit/tree order everywhere.
template<bool TR>
__global__ __launch_bounds__(NTHR, 1)
void glif_kernel(const float* __restrict__ x_seq, const float* __restrict__ w,
                 const float* __restrict__ b_in, const float* __restrict__ v0,
                 const float* __restrict__ Ia0, const float* __restrict__ vth_in,
                 const float* __restrict__ vrst_in, const float* __restrict__ vrest_in,
                 const float* __restrict__ cm_in, const float* __restrict__ tau_in,
                 const float* __restrict__ k_in, const float* __restrict__ asc_in,
                 const float* __restrict__ mask_in,
                 float* __restrict__ out_s, float* __restrict__ out_v,
                 float* __restrict__ out_vf, float* __restrict__ out_if,
                 u64* __restrict__ sbuf, unsigned* __restrict__ bar,
                 float* __restrict__ wT)
{
    __shared__ float    tile[64][65];          // transpose staging (phase 0)
    __shared__ int      wlist[NGW][512];       // per-gather-wave column lists
    __shared__ float4   partials[4][NGW][16];  // 4-deep ring of GEMV partials
    __shared__ unsigned flags[NGW];            // monotonic step tags

    const int blk = blockIdx.x;
    const int tid = threadIdx.x;
    const int n0 = blk * NPB;
    const int wv = tid >> 6;                   // wave 0..8
    const int ln = tid & 63;

    // ---- Phase 0: transpose w -> wT, folding mask into columns
    // (w[n][j]*mask[j] rounds identically to the reference's product w/ s=mask)
    if (TR) {
        for (int tt = 0; tt < 64; ++tt) {
            int tile_id = blk + tt * NBLK;     // 4096 tiles of 64x64
            int ti = tile_id >> 6, tj = tile_id & 63;
            if (tid < 512) {
                int c = tid & 63, r0 = tid >> 6;
#pragma unroll
                for (int rr = 0; rr < 8; ++rr) {
                    int r = r0 + rr * 8;
                    tile[r][c] = w[(size_t)(ti * 64 + r) * BN + tj * 64 + c];
                }
            }
            __syncthreads();
            if (tid < 512) {
                int rw = tid & 63, c0 = tid >> 6;
#pragma unroll
                for (int cc = 0; cc < 8; ++cc) {
                    int cw = c0 + cc * 8;
                    float mcol = mask_in[tj * 64 + cw];
                    wT[(size_t)(tj * 64 + cw) * BN + ti * 64 + rw] = tile[rw][cw] * mcol;
                }
            }
            __syncthreads();
        }
    }

    if (tid < NGW) flags[tid] = 0;

    // ---- single grid barrier: wT complete before step loop
    __syncthreads();
    if (tid == 0) {
        __threadfence();
        __hip_atomic_fetch_add(bar, 1u, __ATOMIC_ACQ_REL, __HIP_MEMORY_SCOPE_AGENT);
        while (__hip_atomic_load(bar, __ATOMIC_RELAXED, __HIP_MEMORY_SCOPE_AGENT) < NBLK) {
            __builtin_amdgcn_s_sleep(8);
        }
        __threadfence();
    }
    __syncthreads();

    if (wv == 0) {
        // ================= WAVE 0: pure updater =================
        const int n = n0 + ln;
        float v, I0, I1, bb, aa, bd0, bd1, as0, as1, vth, vrst, vrest, cm, tau, msk;
        v = v0[n]; I0 = Ia0[2 * n]; I1 = Ia0[2 * n + 1];
        bb = b_in[n]; vth = vth_in[n]; vrst = vrst_in[n]; vrest = vrest_in[n];
        cm = cm_in[n]; tau = tau_in[n]; msk = mask_in[n];
        aa  = (float)exp((double)(-1.0f / tau));
        bd0 = (float)exp((double)(-k_in[2 * n]));
        bd1 = (float)exp((double)(-k_in[2 * n + 1]));
        as0 = asc_in[2 * n]; as1 = asc_in[2 * n + 1];

        for (int t = 0; t < TSTEPS; ++t) {
            float xt = x_seq[(size_t)t * BN + n];       // overlaps flag wait

            {   // lanes spin on one flag each (8 flags, lanes mirror mod 8)
                const unsigned want = (unsigned)(t + 1);
                const unsigned* fp = &flags[ln & 7];
                while (ld_flag(fp) < want) {}
            }
            const float* pf = reinterpret_cast<const float*>(&partials[t & 3][0][0]);
            float l0 = pf[ln],        l1 = pf[64 + ln],  l2 = pf[128 + ln], l3 = pf[192 + ln];
            float l4 = pf[256 + ln],  l5 = pf[320 + ln], l6 = pf[384 + ln], l7 = pf[448 + ln];
            float lin = ((l0 + l1) + (l2 + l3)) + ((l4 + l5) + (l6 + l7));
            float xx = (xt + bb) + lin;
            float Isum = I0 + I1;
            float vinf = vrest + (tau * (xx + Isum)) / cm;
            float vp = vinf + (v - vinf) * aa;
            float uu = (vp - vth) / (vth - vrst);
            float s = (uu > 0.0f) ? msk : 0.0f;
            u64 bal = __ballot(s != 0.0f);              // bit l = neuron n0+l
            u64 tagw = ((u64)(t + 1)) << 32;
            u64* dst = sbuf + ((size_t)((t + 1) & 1) * NBLK + blk) * ESTRIDE;
            if (ln < 2) st_agent(dst + ln, tagw | (u64)(unsigned)(bal >> (32 * ln)));
            float vpost = vp - (vp - vrst) * s;         // HARD_RESET
            I0 = I0 * bd0 + as0 * s;
            I1 = I1 * bd1 + as1 * s;
            v = vpost;
            out_s[(size_t)t * BN + n] = s;
            out_v[(size_t)t * BN + n] = vpost;
        }
        out_vf[n] = v;
        out_if[2 * n] = I0;
        out_if[2 * n + 1] = I1;
    } else {
        // ================= WAVES 1..8: free-running gather =================
        const int gw = wv - 1;
        const int e = ln >> 3;                  // entry within this wave's 8
        const int sub = ln & 7;                 // byte 0..7 of the 64-bit mask
        const int wsel = sub >> 2;              // tagged word 0 or 1
        const int bshift = 8 * (sub & 3);
        const int entry = gw * 8 + e;
        const int cbase = (entry << 6) + (sub << 3);
        const int cslot = ln >> 4, l16 = ln & 15;  // 4 cols/round, 16 lanes/col
        const float* wb4 = wT + n0 + l16 * 4;

        for (int t = 0; t < TSTEPS; ++t) {
            // ---- busy-spin poll, 2 loads in flight
            const u64* p = sbuf + ((size_t)(t & 1) * NBLK + entry) * ESTRIDE + wsel;
            const unsigned want = (unsigned)t;
            u64 ev;
            for (;;) {
                u64 A = ld_agent(p);
                u64 B = ld_agent(p);
                if ((unsigned)(A >> 32) == want) { ev = A; break; }
                if ((unsigned)(B >> 32) == want) { ev = B; break; }
            }
            unsigned byte = ((unsigned)ev >> bshift) & 0xFFu;

            // ---- in-wave compaction (fixed order => deterministic)
            int c = __popc(byte);
            int x = c;
#pragma unroll
            for (int d = 1; d < 64; d <<= 1) {
                int y = __shfl_up(x, d);
                if (ln >= d) x += y;
            }
            const int kw = __shfl(x, 63);
            int base = x - c;
            while (byte) { int bp = __ffs(byte) - 1; byte &= byte - 1; wlist[gw][base++] = cbase + bp; }

            // ---- pipelined gather-GEMV over this wave's columns
            if (TR) {
                float4 acc = make_float4(0.f, 0.f, 0.f, 0.f);
                const int R = (kw + 3) >> 2;     // rounds of 4 columns
                for (int r = 0; r < R; r += 8) {
#pragma unroll
                    for (int u = 0; u < 8; ++u) {
                        int idx = (r + u) * 4 + cslot;
                        bool pg = idx < kw;
                        int j = wlist[gw][pg ? idx : 0];
                        float m = pg ? 1.0f : 0.0f;
                        const float4 wvv = *reinterpret_cast<const float4*>(wb4 + ((size_t)j << 12));
                        acc.x = fmaf(wvv.x, m, acc.x);
                        acc.y = fmaf(wvv.y, m, acc.y);
                        acc.z = fmaf(wvv.z, m, acc.z);
                        acc.w = fmaf(wvv.w, m, acc.w);
                    }
                }
#pragma unroll
                for (int d = 16; d < 64; d <<= 1) {
                    acc.x += __shfl_xor(acc.x, d);
                    acc.y += __shfl_xor(acc.y, d);
                    acc.z += __shfl_xor(acc.z, d);
                    acc.w += __shfl_xor(acc.w, d);
                }
                if (ln < 16) partials[t & 3][gw][ln] = acc;
            } else {
                float accs = 0.f;
                const float* wrow = w + (size_t)(n0 + ln) * BN;
                for (int i = 0; i < kw; ++i) {
                    int j = wlist[gw][i];
                    accs = fmaf(wrow[j], mask_in[j], accs);
                }
                reinterpret_cast<float*>(&partials[t & 3][gw][0])[ln] = accs;
            }
            if (ln == 0) st_flag(&flags[gw], (unsigned)(t + 1));  // release
        }
    }
}

extern "C" void kernel_launch(void* const* d_in, const int* in_sizes, int n_in,
                              void* d_out, int out_size, void* d_ws, size_t ws_size,
                              hipStream_t stream)
{
    const float* x_seq = (const float*)d_in[0];
    const float* w     = (const float*)d_in[1];
    const float* b     = (const float*)d_in[2];
    const float* v0    = (const float*)d_in[3];
    const float* Ia0   = (const float*)d_in[4];
    const float* vth   = (const float*)d_in[5];
    const float* vrst  = (const float*)d_in[6];
    const float* vrest = (const float*)d_in[7];
    const float* cm    = (const float*)d_in[8];
    const float* tau   = (const float*)d_in[9];
    const float* k     = (const float*)d_in[10];
    const float* asc   = (const float*)d_in[11];
    const float* mask  = (const float*)d_in[12];

    float* out_s  = (float*)d_out;
    float* out_v  = out_s + (size_t)TSTEPS * BN;
    float* out_vf = out_v + (size_t)TSTEPS * BN;
    float* out_if = out_vf + BN;

    // mailbox: 2 parities x 64 blocks x 128-B line = 16 KiB
    const size_t mb_bytes = (size_t)2 * NBLK * ESTRIDE * sizeof(u64);
    u64* sbuf     = (u64*)d_ws;
    unsigned* bar = (unsigned*)((char*)d_ws + mb_bytes);
    float* wT     = (float*)((char*)d_ws + mb_bytes + 256);

    const size_t need = mb_bytes + 256 + (size_t)BN * BN * sizeof(float);
    const bool tr = (ws_size >= need);

    // zero mailbox tags + barrier counter (inside graph -> resets every replay)
    hipMemsetAsync(d_ws, 0, mb_bytes + 256, stream);

    if (tr) {
        glif_kernel<true><<<NBLK, NTHR, 0, stream>>>(
            x_seq, w, b, v0, Ia0, vth, vrst, vrest, cm, tau, k, asc, mask,
            out_s, out_v, out_vf, out_if, sbuf, bar, wT);
    } else {
        glif_kernel<false><<<NBLK, NTHR, 0, stream>>>(
            x_seq, w, b, v0, Ia0, vth, vrst, vrest, cm, tau, k, asc, mask,
            out_s, out_v, out_vf, out_if, sbuf, bar, (float*)w);
    }
}